// Round 5
// baseline (39.715 us; speedup 1.0000x reference)
//
#include <hip/hip_runtime.h>

#define INFV 3.0e38f
#define NBLOCKS 323
#define CNTBASE 0x7F7F7F7Fu

// ws layout (u32/float indices)
#define D1MIN 0        // 16*1024 final min d^2 via atomicMin (uint bitpattern)
#define D2MIN 16384    // 16*1024
#define CDMIN 32768    // 16*96 (padded 1536)
#define ACC   34304    // slots:
#define S_DIV  (ACC + 0)   // 16 per-batch div partials
#define S_DEL  (ACC + 16)  // 16 delta partials
#define S_POSE (ACC + 32)
#define S_NOCS (ACC + 33)
#define S_DIST (ACC + 34)
#define S_CNT  (ACC + 60)  // counter (u32), init CNTBASE by ws_init each call
#define INIT_U32 34816     // 34 blocks * 256 thr * 4 u32

__device__ __forceinline__ float wave_reduce_sum(float v) {
#pragma unroll
    for (int m = 1; m < 64; m <<= 1) v += __shfl_xor(v, m);
    return v;
}

// returns full block sum to ALL threads (256-thread block)
__device__ __forceinline__ float block_sum_t0(float v, float* sbuf) {
    v = wave_reduce_sum(v);
    int lane = threadIdx.x & 63, wid = threadIdx.x >> 6;
    if (lane == 0) sbuf[wid] = v;
    __syncthreads();
    return sbuf[0] + sbuf[1] + sbuf[2] + sbuf[3];
}

__device__ __forceinline__ float agent_load_f(const float* p) {
    return __hip_atomic_load(p, __ATOMIC_RELAXED, __HIP_MEMORY_SCOPE_AGENT);
}
__device__ __forceinline__ void agent_store_f(float* p, float v) {
    __hip_atomic_store(p, v, __ATOMIC_RELAXED, __HIP_MEMORY_SCOPE_AGENT);
}

// pc_mask may arrive as u8 (1B) or i32 (4B). Probe bytes at 4i+1 (wave-wide).
__device__ __forceinline__ bool mask_mode_u8(const void* mp) {
    const unsigned char* p = (const unsigned char*)mp;
    unsigned char v = p[(threadIdx.x & 63) * 4 + 1];
    return __ballot(v != 0) != 0ull;
}
__device__ __forceinline__ bool mask_at(const void* mp, int idx, bool u8) {
    if (u8) return ((const unsigned char*)mp)[idx] != 0;
    return ((const int*)mp)[idx] != 0;
}

__global__ __launch_bounds__(256) void ws_init(uint4* __restrict__ p) {
    p[blockIdx.x * 256 + threadIdx.x] =
        make_uint4(CNTBASE, CNTBASE, CNTBASE, CNTBASE);
}

__global__ __launch_bounds__(256) void loss_main(
    const float* __restrict__ pts,          // (16,1024,3)
    const float* __restrict__ recon_delta,  // (16,1024,3)
    const float* __restrict__ kpt,          // (16,96,3)
    const float* __restrict__ recon,        // (16,1024,3)
    const float* __restrict__ t_label,      // (16,3)
    const float* __restrict__ r_label,      // (16,3,3)
    const float* __restrict__ s_label,      // (16,3)
    const float* __restrict__ pred_r,       // (16,3,3)
    const float* __restrict__ pred_t,       // (16,3)
    const float* __restrict__ pred_s,       // (16,3)
    const float* __restrict__ kpt_nocs,     // (16,96,3)
    const void*  __restrict__ pc_mask,      // (16,1024) bool
    const float* __restrict__ d_pn,         // (16,512)
    const float* __restrict__ d_ul,         // (16,512)
    float* __restrict__ ws,
    float* __restrict__ out)
{
    __shared__ float4 lds4[512];
    __shared__ float sbuf[8];
    __shared__ float red[16];
    __shared__ unsigned lastFlag;
    const int t = threadIdx.x;
    const int blk = blockIdx.x;

    if (blk < 128) {
        // ---- d1: block=(b,jc). Stage 128 recon pts + ||r||^2 in .w.
        int b = blk >> 3, jc = blk & 7;
        if (t < 128) {
            const float* g = recon + ((b << 10) + jc * 128 + t) * 3;
            float x = g[0], y = g[1], z = g[2];
            lds4[t] = make_float4(x, y, z, fmaf(x, x, fmaf(y, y, z * z)));
        }
        __syncthreads();
        float ax[4], ay[4], az[4], pp[4], smin[4];
#pragma unroll
        for (int p = 0; p < 4; ++p) {
            const float* P = pts + ((b << 10) + t + (p << 8)) * 3;
            float x = P[0], y = P[1], z = P[2];
            ax[p] = -2.0f * x; ay[p] = -2.0f * y; az[p] = -2.0f * z;
            pp[p] = fmaf(x, x, fmaf(y, y, z * z));
            smin[p] = INFV;
        }
#pragma unroll 8
        for (int j = 0; j < 128; ++j) {
            float4 r = lds4[j];
#pragma unroll
            for (int p = 0; p < 4; ++p) {
                float s = fmaf(ax[p], r.x, fmaf(ay[p], r.y, fmaf(az[p], r.z, r.w)));
                smin[p] = fminf(smin[p], s);
            }
        }
        unsigned* dst = (unsigned*)ws + D1MIN + (b << 10);
#pragma unroll
        for (int p = 0; p < 4; ++p) {
            float d2v = fmaxf(0.0f, pp[p] + smin[p]);
            atomicMin(dst + t + (p << 8), __float_as_uint(d2v));
        }

    } else if (blk < 256) {
        // ---- d2: block=(b,ic). Stage 128 pts (masked -> (0,0,0,3e36)).
        int bb = blk - 128;
        int b = bb >> 3, ic = bb & 7;
        bool u8 = mask_mode_u8(pc_mask);
        if (t < 128) {
            int i = ic * 128 + t;
            const float* P = pts + ((b << 10) + i) * 3;
            bool m = mask_at(pc_mask, (b << 10) + i, u8);
            float x = P[0], y = P[1], z = P[2];
            lds4[t] = m ? make_float4(x, y, z, fmaf(x, x, fmaf(y, y, z * z)))
                        : make_float4(0.0f, 0.0f, 0.0f, 3.0e36f);
        }
        __syncthreads();
        float ax[4], ay[4], az[4], pp[4], smin[4];
#pragma unroll
        for (int p = 0; p < 4; ++p) {
            const float* R = recon + ((b << 10) + t + (p << 8)) * 3;
            float x = R[0], y = R[1], z = R[2];
            ax[p] = -2.0f * x; ay[p] = -2.0f * y; az[p] = -2.0f * z;
            pp[p] = fmaf(x, x, fmaf(y, y, z * z));
            smin[p] = INFV;
        }
#pragma unroll 8
        for (int i = 0; i < 128; ++i) {
            float4 q = lds4[i];
#pragma unroll
            for (int p = 0; p < 4; ++p) {
                float s = fmaf(ax[p], q.x, fmaf(ay[p], q.y, fmaf(az[p], q.z, q.w)));
                smin[p] = fminf(smin[p], s);
            }
        }
        unsigned* dst = (unsigned*)ws + D2MIN + (b << 10);
#pragma unroll
        for (int p = 0; p < 4; ++p) {
            float d2v = fmaxf(0.0f, pp[p] + smin[p]);
            atomicMin(dst + t + (p << 8), __float_as_uint(d2v));
        }

    } else if (blk < 288) {
        // ---- cd: block=(b, half). Stage 512 pts + rr; t<192 -> (quarter q, k).
        int bb = blk - 256;
        int b = bb >> 1, ih = bb & 1;
        const float* src = pts + ((b << 10) + ih * 512) * 3;
        for (int e = t; e < 512; e += 256) {
            const float* g = src + e * 3;
            float x = g[0], y = g[1], z = g[2];
            lds4[e] = make_float4(x, y, z, fmaf(x, x, fmaf(y, y, z * z)));
        }
        __syncthreads();
        if (t < 192) {
            int q = t / 96, k = t - q * 96;
            const float* K = kpt + (b * 96 + k) * 3;
            float x = K[0], y = K[1], z = K[2];
            float ax = -2.0f * x, ay = -2.0f * y, az = -2.0f * z;
            float pp = fmaf(x, x, fmaf(y, y, z * z));
            float smin = INFV;
            int base = q << 8;
#pragma unroll 8
            for (int i = 0; i < 256; ++i) {
                float4 p4 = lds4[base + i];
                float s = fmaf(ax, p4.x, fmaf(ay, p4.y, fmaf(az, p4.z, p4.w)));
                smin = fminf(smin, s);
            }
            float d2v = fmaxf(0.0f, pp + smin);
            atomicMin((unsigned*)ws + CDMIN + b * 96 + k, __float_as_uint(d2v));
        }

    } else if (blk < 304) {
        // ---- diversity per batch
        int b = blk - 288;
        const float* K = kpt + b * 288;
        if (t < 96) lds4[t] = make_float4(K[t * 3], K[t * 3 + 1], K[t * 3 + 2], 0.0f);
        __syncthreads();
        float acc = 0.0f;
        for (int r = 0; r < 36; ++r) {
            int p = r * 256 + t;
            int ki = p / 96, kj = p - ki * 96;
            float4 a = lds4[ki], c = lds4[kj];
            float dx = a.x - c.x, dy = a.y - c.y, dz = a.z - c.z;
            float d = sqrtf(dx * dx + dy * dy + dz * dz + 1e-12f);
            if (ki != kj && d < 0.1f) acc += 1.0f - d * 10.0f;
        }
        float s = block_sum_t0(acc, sbuf);
        if (t == 0) agent_store_f(ws + S_DIV + b, s);

    } else if (blk < 320) {
        // ---- recon_delta norms
        int e = blk - 304;
        float acc = 0.0f;
#pragma unroll
        for (int r = 0; r < 4; ++r) {
            const float* D = recon_delta + (e * 1024 + r * 256 + t) * 3;
            acc += sqrtf(D[0] * D[0] + D[1] * D[1] + D[2] * D[2]);
        }
        float s = block_sum_t0(acc, sbuf);
        if (t == 0) agent_store_f(ws + S_DEL + (blk - 304), s);

    } else if (blk == 320) {
        // ---- pose (fully normalized)
        float c = 0.0f;
        if (t < 48) {
            int b = t / 3, j = t - b * 3;
            float s = 0.0f;
#pragma unroll
            for (int i2 = 0; i2 < 3; ++i2) {
                float d = pred_r[b * 9 + i2 * 3 + j] - r_label[b * 9 + i2 * 3 + j];
                s += d * d;
            }
            c = sqrtf(s) * (1.0f / 48.0f);
        } else if (t >= 64 && t < 80) {
            int b = t - 64;
            float s = 0.0f;
#pragma unroll
            for (int d2i = 0; d2i < 3; ++d2i) {
                float d = pred_t[b * 3 + d2i] - t_label[b * 3 + d2i];
                s += d * d;
            }
            c = sqrtf(s) * (1.0f / 16.0f);
        } else if (t >= 96 && t < 112) {
            int b = t - 96;
            float s = 0.0f;
#pragma unroll
            for (int d2i = 0; d2i < 3; ++d2i) {
                float d = pred_s[b * 3 + d2i] - s_label[b * 3 + d2i];
                s += d * d;
            }
            c = sqrtf(s) * (1.0f / 16.0f);
        }
        float s = block_sum_t0(c, sbuf);
        if (t == 0) agent_store_f(ws + S_POSE, s);

    } else if (blk == 321) {
        // ---- NOCS smooth-L1
        float acc = 0.0f;
#pragma unroll
        for (int r = 0; r < 6; ++r) {
            int item = r * 256 + t;
            int b = item / 96, k = item - b * 96;
            float sx = s_label[b * 3], sy = s_label[b * 3 + 1], sz = s_label[b * 3 + 2];
            float sn = sqrtf(sx * sx + sy * sy + sz * sz) + 1e-8f;
            float v0 = (kpt[(b * 96 + k) * 3 + 0] - t_label[b * 3 + 0]) / sn;
            float v1 = (kpt[(b * 96 + k) * 3 + 1] - t_label[b * 3 + 1]) / sn;
            float v2 = (kpt[(b * 96 + k) * 3 + 2] - t_label[b * 3 + 2]) / sn;
#pragma unroll
            for (int e = 0; e < 3; ++e) {
                float gt = v0 * r_label[b * 9 + e] + v1 * r_label[b * 9 + 3 + e] +
                           v2 * r_label[b * 9 + 6 + e];
                float diff = fabsf(kpt_nocs[(b * 96 + k) * 3 + e] - gt);
                acc += (diff > 0.1f) ? (diff - 0.05f) : (diff * diff * 5.0f);
            }
        }
        float s = block_sum_t0(acc, sbuf);
        if (t == 0) agent_store_f(ws + S_NOCS, s);

    } else {
        // ---- distillation
        int b = t >> 4, off = t & 15;
        float s = 0.0f;
        for (int c2 = off; c2 < 512; c2 += 16) {
            float d = d_pn[b * 512 + c2] - d_ul[b * 512 + c2];
            s += d * d;
        }
        s += __shfl_xor(s, 1);
        s += __shfl_xor(s, 2);
        s += __shfl_xor(s, 4);
        s += __shfl_xor(s, 8);
        float c = (off == 0) ? sqrtf(s) : 0.0f;
        float sm = block_sum_t0(c, sbuf);
        if (t == 0) agent_store_f(ws + S_DIST, sm);
    }

    // ---- last-block gate (release: threadfence + atomicAdd)
    __syncthreads();
    if (t == 0) {
        __threadfence();
        unsigned old = atomicAdd((unsigned*)ws + S_CNT, 1u);
        lastFlag = ((old - CNTBASE) == (NBLOCKS - 1)) ? 1u : 0u;
    }
    __syncthreads();
    if (!lastFlag) return;
    __threadfence();   // acquire: invalidate caches so plain loads see final values

    // ================= phase 2 (single block), plain vectorized loads =========
    bool u8 = mask_mode_u8(pc_mask);

    // d1 per-batch masked mean: 16 threads per batch; u8 branch hoisted (uniform)
    int b16 = t >> 4, l16 = t & 15;
    float s1 = 0.0f, s2 = 0.0f;
    const uint4* w4 = (const uint4*)ws;          // D1MIN == 0
    if (u8) {
#pragma unroll
        for (int r = 0; r < 16; ++r) {
            int idx4 = (b16 << 8) + (r << 4) + l16;
            uint4 v = w4[idx4];
            unsigned mb = ((const unsigned*)pc_mask)[idx4];
            if (mb & 0x000000ffu) { s1 += sqrtf(__uint_as_float(v.x)); s2 += 1.0f; }
            if (mb & 0x0000ff00u) { s1 += sqrtf(__uint_as_float(v.y)); s2 += 1.0f; }
            if (mb & 0x00ff0000u) { s1 += sqrtf(__uint_as_float(v.z)); s2 += 1.0f; }
            if (mb & 0xff000000u) { s1 += sqrtf(__uint_as_float(v.w)); s2 += 1.0f; }
        }
    } else {
#pragma unroll
        for (int r = 0; r < 16; ++r) {
            int idx4 = (b16 << 8) + (r << 4) + l16;
            uint4 v = w4[idx4];
            uint4 mi = ((const uint4*)pc_mask)[idx4];
            if (mi.x) { s1 += sqrtf(__uint_as_float(v.x)); s2 += 1.0f; }
            if (mi.y) { s1 += sqrtf(__uint_as_float(v.y)); s2 += 1.0f; }
            if (mi.z) { s1 += sqrtf(__uint_as_float(v.z)); s2 += 1.0f; }
            if (mi.w) { s1 += sqrtf(__uint_as_float(v.w)); s2 += 1.0f; }
        }
    }
#pragma unroll
    for (int m = 1; m < 16; m <<= 1) {
        s1 += __shfl_xor(s1, m);
        s2 += __shfl_xor(s2, m);
    }
    if (l16 == 0) red[b16] = 0.5f * s1 / s2;

    // d2 total: uint4 loads, lane-contiguous
    float sA = 0.0f;
    const uint4* w4d2 = (const uint4*)(ws + D2MIN);
#pragma unroll
    for (int r = 0; r < 16; ++r) {
        uint4 v = w4d2[(r << 8) + t];
        sA += sqrtf(__uint_as_float(v.x)) + sqrtf(__uint_as_float(v.y)) +
              sqrtf(__uint_as_float(v.z)) + sqrtf(__uint_as_float(v.w));
    }
    // cd total: 1536 elements = 256*uint4 + 256*uint2
    float sC = 0.0f;
    {
        uint4 v = ((const uint4*)(ws + CDMIN))[t];
        sC += sqrtf(__uint_as_float(v.x)) + sqrtf(__uint_as_float(v.y)) +
              sqrtf(__uint_as_float(v.z)) + sqrtf(__uint_as_float(v.w));
        uint2 v2 = ((const uint2*)(ws + CDMIN + 1024))[t];
        sC += sqrtf(__uint_as_float(v2.x)) + sqrtf(__uint_as_float(v2.y));
    }

    sA = wave_reduce_sum(sA);
    sC = wave_reduce_sum(sC);
    int lane = t & 63, wid = t >> 6;
    if (lane == 0) { sbuf[wid] = sA; sbuf[4 + wid] = sC; }
    __syncthreads();

    if (t == 0) {
        float d2sum = sbuf[0] + sbuf[1] + sbuf[2] + sbuf[3];
        float cdsum = sbuf[4] + sbuf[5] + sbuf[6] + sbuf[7];
        float d1part = 0.0f;
#pragma unroll
        for (int b = 0; b < 16; ++b) d1part += red[b];
        float divs = 0.0f, dels = 0.0f;
#pragma unroll
        for (int q = 0; q < 16; ++q) {
            divs += agent_load_f(ws + S_DIV + q);
            dels += agent_load_f(ws + S_DEL + q);
        }
        float pose  = agent_load_f(ws + S_POSE);
        float nocs  = agent_load_f(ws + S_NOCS) * (1.0f / 1536.0f);
        float dist  = agent_load_f(ws + S_DIST) * (1.0f / 16.0f);
        float recon = d1part * (1.0f / 16.0f) + 0.5f * d2sum * (1.0f / 16384.0f);
        float cd    = cdsum * (1.0f / 1536.0f);
        float divl  = divs * (1.0f / (9120.0f * 16.0f));
        float delta = dels * (1.0f / 16384.0f);
        float all = pose + nocs + cd + divl + recon + delta + dist;
        out[0] = all;  out[1] = pose;  out[2] = nocs;  out[3] = cd;
        out[4] = divl; out[5] = recon; out[6] = delta; out[7] = dist;
    }
}

extern "C" void kernel_launch(void* const* d_in, const int* in_sizes, int n_in,
                              void* d_out, int out_size, void* d_ws, size_t ws_size,
                              hipStream_t stream) {
    float* ws = (float*)d_ws;
    ws_init<<<INIT_U32 / (256 * 4), 256, 0, stream>>>((uint4*)d_ws);
    loss_main<<<NBLOCKS, 256, 0, stream>>>(
        (const float*)d_in[0],  (const float*)d_in[1],  (const float*)d_in[2],
        (const float*)d_in[3],  (const float*)d_in[4],  (const float*)d_in[5],
        (const float*)d_in[6],  (const float*)d_in[7],  (const float*)d_in[8],
        (const float*)d_in[9],  (const float*)d_in[10], (const void*)d_in[11],
        (const float*)d_in[12], (const float*)d_in[13], ws, (float*)d_out);
}

// Round 6
// 36.594 us; speedup vs baseline: 1.0853x; 1.0853x over previous
//
#include <hip/hip_runtime.h>

#define INFV 3.0e38f
#define NBLOCKS 611
#define CNTBASE 0x7F7F7F7Fu

// ws layout (u32/float indices)
#define D1MIN 0        // 16*1024 final min d^2 via atomicMin (uint bitpattern)
#define D2MIN 16384    // 16*1024
#define CDMIN 32768    // 16*96 (padded 1536)
#define ACC   34304
#define S_DIV  (ACC + 0)   // 16 per-batch div partials
#define S_DEL  (ACC + 16)  // 16 delta partials
#define S_POSE (ACC + 32)
#define S_NOCS (ACC + 33)
#define S_DIST (ACC + 34)
#define S_CNT  (ACC + 60)
#define INIT_U32 34816     // 34 blocks * 256 thr * 4 u32

__device__ __forceinline__ float wave_reduce_sum(float v) {
#pragma unroll
    for (int m = 1; m < 64; m <<= 1) v += __shfl_xor(v, m);
    return v;
}

__device__ __forceinline__ float block_sum_t0(float v, float* sbuf) {
    v = wave_reduce_sum(v);
    int lane = threadIdx.x & 63, wid = threadIdx.x >> 6;
    if (lane == 0) sbuf[wid] = v;
    __syncthreads();
    return sbuf[0] + sbuf[1] + sbuf[2] + sbuf[3];
}

__device__ __forceinline__ float agent_load_f(const float* p) {
    return __hip_atomic_load(p, __ATOMIC_RELAXED, __HIP_MEMORY_SCOPE_AGENT);
}
__device__ __forceinline__ void agent_store_f(float* p, float v) {
    __hip_atomic_store(p, v, __ATOMIC_RELAXED, __HIP_MEMORY_SCOPE_AGENT);
}

// pc_mask may arrive as u8 (1B) or i32 (4B). Probe bytes at 4i+1 (wave-wide).
__device__ __forceinline__ bool mask_mode_u8(const void* mp) {
    const unsigned char* p = (const unsigned char*)mp;
    unsigned char v = p[(threadIdx.x & 63) * 4 + 1];
    return __ballot(v != 0) != 0ull;
}
__device__ __forceinline__ bool mask_at(const void* mp, int idx, bool u8) {
    if (u8) return ((const unsigned char*)mp)[idx] != 0;
    return ((const int*)mp)[idx] != 0;
}

__global__ __launch_bounds__(256) void ws_init(uint4* __restrict__ p) {
    p[blockIdx.x * 256 + threadIdx.x] =
        make_uint4(CNTBASE, CNTBASE, CNTBASE, CNTBASE);
}

// load a point and derive (-2x,-2y,-2z, ||p||^2)
#define LOADP(Pp, AX, AY, AZ, PP) { \
    float x_ = (Pp)[0], y_ = (Pp)[1], z_ = (Pp)[2]; \
    AX = -2.0f * x_; AY = -2.0f * y_; AZ = -2.0f * z_; \
    PP = fmaf(x_, x_, fmaf(y_, y_, z_ * z_)); }

// one staged point vs 4 accumulator chains
#define DSTEP(r) { \
    m0 = fminf(m0, fmaf(ax0, (r).x, fmaf(ay0, (r).y, fmaf(az0, (r).z, (r).w)))); \
    m1 = fminf(m1, fmaf(ax1, (r).x, fmaf(ay1, (r).y, fmaf(az1, (r).z, (r).w)))); \
    m2 = fminf(m2, fmaf(ax2, (r).x, fmaf(ay2, (r).y, fmaf(az2, (r).z, (r).w)))); \
    m3 = fminf(m3, fmaf(ax3, (r).x, fmaf(ay3, (r).y, fmaf(az3, (r).z, (r).w)))); }

#define CSTEP(r) { \
    smin = fminf(smin, fmaf(ax, (r).x, fmaf(ay, (r).y, fmaf(az, (r).z, (r).w)))); }

__global__ __launch_bounds__(256) void loss_main(
    const float* __restrict__ pts,          // (16,1024,3)
    const float* __restrict__ recon_delta,  // (16,1024,3)
    const float* __restrict__ kpt,          // (16,96,3)
    const float* __restrict__ recon,        // (16,1024,3)
    const float* __restrict__ t_label,      // (16,3)
    const float* __restrict__ r_label,      // (16,3,3)
    const float* __restrict__ s_label,      // (16,3)
    const float* __restrict__ pred_r,       // (16,3,3)
    const float* __restrict__ pred_t,       // (16,3)
    const float* __restrict__ pred_s,       // (16,3)
    const float* __restrict__ kpt_nocs,     // (16,96,3)
    const void*  __restrict__ pc_mask,      // (16,1024) bool
    const float* __restrict__ d_pn,         // (16,512)
    const float* __restrict__ d_ul,         // (16,512)
    float* __restrict__ ws,
    float* __restrict__ out)
{
    __shared__ float4 lds4[256];
    __shared__ float sbuf[8];
    __shared__ float red[16];
    __shared__ unsigned lastFlag;
    const int t = threadIdx.x;
    const int blk = blockIdx.x;

    if (blk < 256) {
        // ---- d1: block=(b, jc of 16). Stage 64 recon pts; thread owns 4 pts.
        int b = blk >> 4, jc = blk & 15;
        if (t < 64) {
            const float* g = recon + ((b << 10) + (jc << 6) + t) * 3;
            float x = g[0], y = g[1], z = g[2];
            lds4[t] = make_float4(x, y, z, fmaf(x, x, fmaf(y, y, z * z)));
        }
        __syncthreads();
        float ax0, ay0, az0, pp0, ax1, ay1, az1, pp1;
        float ax2, ay2, az2, pp2, ax3, ay3, az3, pp3;
        const float* P = pts + ((b << 10) + t) * 3;
        LOADP(P, ax0, ay0, az0, pp0);
        LOADP(P + 768, ax1, ay1, az1, pp1);
        LOADP(P + 1536, ax2, ay2, az2, pp2);
        LOADP(P + 2304, ax3, ay3, az3, pp3);
        float m0 = INFV, m1 = INFV, m2 = INFV, m3 = INFV;
        for (int j = 0; j < 64; j += 8) {
            float4 r0 = lds4[j + 0], r1 = lds4[j + 1];
            float4 r2 = lds4[j + 2], r3 = lds4[j + 3];
            float4 r4 = lds4[j + 4], r5 = lds4[j + 5];
            float4 r6 = lds4[j + 6], r7 = lds4[j + 7];
            DSTEP(r0) DSTEP(r1) DSTEP(r2) DSTEP(r3)
            DSTEP(r4) DSTEP(r5) DSTEP(r6) DSTEP(r7)
        }
        unsigned* dst = (unsigned*)ws + D1MIN + (b << 10) + t;
        atomicMin(dst, __float_as_uint(fmaxf(0.0f, pp0 + m0)));
        atomicMin(dst + 256, __float_as_uint(fmaxf(0.0f, pp1 + m1)));
        atomicMin(dst + 512, __float_as_uint(fmaxf(0.0f, pp2 + m2)));
        atomicMin(dst + 768, __float_as_uint(fmaxf(0.0f, pp3 + m3)));

    } else if (blk < 512) {
        // ---- d2: block=(b, ic of 16). Stage 64 pts (masked->(0,0,0,3e36)).
        int bb = blk - 256;
        int b = bb >> 4, ic = bb & 15;
        bool u8 = mask_mode_u8(pc_mask);
        if (t < 64) {
            int i = (ic << 6) + t;
            const float* P = pts + ((b << 10) + i) * 3;
            bool m = mask_at(pc_mask, (b << 10) + i, u8);
            float x = P[0], y = P[1], z = P[2];
            lds4[t] = m ? make_float4(x, y, z, fmaf(x, x, fmaf(y, y, z * z)))
                        : make_float4(0.0f, 0.0f, 0.0f, 3.0e36f);
        }
        __syncthreads();
        float ax0, ay0, az0, pp0, ax1, ay1, az1, pp1;
        float ax2, ay2, az2, pp2, ax3, ay3, az3, pp3;
        const float* R = recon + ((b << 10) + t) * 3;
        LOADP(R, ax0, ay0, az0, pp0);
        LOADP(R + 768, ax1, ay1, az1, pp1);
        LOADP(R + 1536, ax2, ay2, az2, pp2);
        LOADP(R + 2304, ax3, ay3, az3, pp3);
        float m0 = INFV, m1 = INFV, m2 = INFV, m3 = INFV;
        for (int j = 0; j < 64; j += 8) {
            float4 r0 = lds4[j + 0], r1 = lds4[j + 1];
            float4 r2 = lds4[j + 2], r3 = lds4[j + 3];
            float4 r4 = lds4[j + 4], r5 = lds4[j + 5];
            float4 r6 = lds4[j + 6], r7 = lds4[j + 7];
            DSTEP(r0) DSTEP(r1) DSTEP(r2) DSTEP(r3)
            DSTEP(r4) DSTEP(r5) DSTEP(r6) DSTEP(r7)
        }
        unsigned* dst = (unsigned*)ws + D2MIN + (b << 10) + t;
        atomicMin(dst, __float_as_uint(fmaxf(0.0f, pp0 + m0)));
        atomicMin(dst + 256, __float_as_uint(fmaxf(0.0f, pp1 + m1)));
        atomicMin(dst + 512, __float_as_uint(fmaxf(0.0f, pp2 + m2)));
        atomicMin(dst + 768, __float_as_uint(fmaxf(0.0f, pp3 + m3)));

    } else if (blk < 576) {
        // ---- cd: block=(b, quarter ih of 4). Stage 256 pts; t<192: (q, k).
        int bb = blk - 512;
        int b = bb >> 2, ih = bb & 3;
        {
            const float* g = pts + ((b << 10) + (ih << 8) + t) * 3;
            float x = g[0], y = g[1], z = g[2];
            lds4[t] = make_float4(x, y, z, fmaf(x, x, fmaf(y, y, z * z)));
        }
        __syncthreads();
        if (t < 192) {
            int q = t / 96, k = t - q * 96;
            const float* K = kpt + (b * 96 + k) * 3;
            float ax, ay, az, pp;
            LOADP(K, ax, ay, az, pp);
            float smin = INFV;
            int base = q << 7;
            for (int j = 0; j < 128; j += 8) {
                float4 r0 = lds4[base + j + 0], r1 = lds4[base + j + 1];
                float4 r2 = lds4[base + j + 2], r3 = lds4[base + j + 3];
                float4 r4 = lds4[base + j + 4], r5 = lds4[base + j + 5];
                float4 r6 = lds4[base + j + 6], r7 = lds4[base + j + 7];
                CSTEP(r0) CSTEP(r1) CSTEP(r2) CSTEP(r3)
                CSTEP(r4) CSTEP(r5) CSTEP(r6) CSTEP(r7)
            }
            float d2v = fmaxf(0.0f, pp + smin);
            atomicMin((unsigned*)ws + CDMIN + b * 96 + k, __float_as_uint(d2v));
        }

    } else if (blk < 592) {
        // ---- diversity per batch
        int b = blk - 576;
        const float* K = kpt + b * 288;
        if (t < 96) lds4[t] = make_float4(K[t * 3], K[t * 3 + 1], K[t * 3 + 2], 0.0f);
        __syncthreads();
        float acc = 0.0f;
        for (int r = 0; r < 36; ++r) {
            int p = r * 256 + t;
            int ki = p / 96, kj = p - ki * 96;
            float4 a = lds4[ki], c = lds4[kj];
            float dx = a.x - c.x, dy = a.y - c.y, dz = a.z - c.z;
            float d = sqrtf(dx * dx + dy * dy + dz * dz + 1e-12f);
            if (ki != kj && d < 0.1f) acc += 1.0f - d * 10.0f;
        }
        float s = block_sum_t0(acc, sbuf);
        if (t == 0) agent_store_f(ws + S_DIV + b, s);

    } else if (blk < 608) {
        // ---- recon_delta norms
        int e = blk - 592;
        float acc = 0.0f;
#pragma unroll
        for (int r = 0; r < 4; ++r) {
            const float* D = recon_delta + (e * 1024 + r * 256 + t) * 3;
            acc += sqrtf(D[0] * D[0] + D[1] * D[1] + D[2] * D[2]);
        }
        float s = block_sum_t0(acc, sbuf);
        if (t == 0) agent_store_f(ws + S_DEL + e, s);

    } else if (blk == 608) {
        // ---- pose (fully normalized)
        float c = 0.0f;
        if (t < 48) {
            int b = t / 3, j = t - b * 3;
            float s = 0.0f;
#pragma unroll
            for (int i2 = 0; i2 < 3; ++i2) {
                float d = pred_r[b * 9 + i2 * 3 + j] - r_label[b * 9 + i2 * 3 + j];
                s += d * d;
            }
            c = sqrtf(s) * (1.0f / 48.0f);
        } else if (t >= 64 && t < 80) {
            int b = t - 64;
            float s = 0.0f;
#pragma unroll
            for (int d2i = 0; d2i < 3; ++d2i) {
                float d = pred_t[b * 3 + d2i] - t_label[b * 3 + d2i];
                s += d * d;
            }
            c = sqrtf(s) * (1.0f / 16.0f);
        } else if (t >= 96 && t < 112) {
            int b = t - 96;
            float s = 0.0f;
#pragma unroll
            for (int d2i = 0; d2i < 3; ++d2i) {
                float d = pred_s[b * 3 + d2i] - s_label[b * 3 + d2i];
                s += d * d;
            }
            c = sqrtf(s) * (1.0f / 16.0f);
        }
        float s = block_sum_t0(c, sbuf);
        if (t == 0) agent_store_f(ws + S_POSE, s);

    } else if (blk == 609) {
        // ---- NOCS smooth-L1
        float acc = 0.0f;
#pragma unroll
        for (int r = 0; r < 6; ++r) {
            int item = r * 256 + t;
            int b = item / 96, k = item - b * 96;
            float sx = s_label[b * 3], sy = s_label[b * 3 + 1], sz = s_label[b * 3 + 2];
            float sn = sqrtf(sx * sx + sy * sy + sz * sz) + 1e-8f;
            float v0 = (kpt[(b * 96 + k) * 3 + 0] - t_label[b * 3 + 0]) / sn;
            float v1 = (kpt[(b * 96 + k) * 3 + 1] - t_label[b * 3 + 1]) / sn;
            float v2 = (kpt[(b * 96 + k) * 3 + 2] - t_label[b * 3 + 2]) / sn;
#pragma unroll
            for (int e = 0; e < 3; ++e) {
                float gt = v0 * r_label[b * 9 + e] + v1 * r_label[b * 9 + 3 + e] +
                           v2 * r_label[b * 9 + 6 + e];
                float diff = fabsf(kpt_nocs[(b * 96 + k) * 3 + e] - gt);
                acc += (diff > 0.1f) ? (diff - 0.05f) : (diff * diff * 5.0f);
            }
        }
        float s = block_sum_t0(acc, sbuf);
        if (t == 0) agent_store_f(ws + S_NOCS, s);

    } else {
        // ---- distillation
        int b = t >> 4, off = t & 15;
        float s = 0.0f;
        for (int c2 = off; c2 < 512; c2 += 16) {
            float d = d_pn[b * 512 + c2] - d_ul[b * 512 + c2];
            s += d * d;
        }
        s += __shfl_xor(s, 1);
        s += __shfl_xor(s, 2);
        s += __shfl_xor(s, 4);
        s += __shfl_xor(s, 8);
        float c = (off == 0) ? sqrtf(s) : 0.0f;
        float sm = block_sum_t0(c, sbuf);
        if (t == 0) agent_store_f(ws + S_DIST, sm);
    }

    // ---- last-block gate (release: threadfence + atomicAdd)
    __syncthreads();
    if (t == 0) {
        __threadfence();
        unsigned old = atomicAdd((unsigned*)ws + S_CNT, 1u);
        lastFlag = ((old - CNTBASE) == (NBLOCKS - 1)) ? 1u : 0u;
    }
    __syncthreads();
    if (!lastFlag) return;
    __threadfence();   // acquire

    // ================= phase 2 (single block), plain vectorized loads =========
    bool u8 = mask_mode_u8(pc_mask);

    int b16 = t >> 4, l16 = t & 15;
    float s1 = 0.0f, s2 = 0.0f;
    const uint4* w4 = (const uint4*)ws;          // D1MIN == 0
    if (u8) {
#pragma unroll
        for (int r = 0; r < 16; ++r) {
            int idx4 = (b16 << 8) + (r << 4) + l16;
            uint4 v = w4[idx4];
            unsigned mb = ((const unsigned*)pc_mask)[idx4];
            if (mb & 0x000000ffu) { s1 += sqrtf(__uint_as_float(v.x)); s2 += 1.0f; }
            if (mb & 0x0000ff00u) { s1 += sqrtf(__uint_as_float(v.y)); s2 += 1.0f; }
            if (mb & 0x00ff0000u) { s1 += sqrtf(__uint_as_float(v.z)); s2 += 1.0f; }
            if (mb & 0xff000000u) { s1 += sqrtf(__uint_as_float(v.w)); s2 += 1.0f; }
        }
    } else {
#pragma unroll
        for (int r = 0; r < 16; ++r) {
            int idx4 = (b16 << 8) + (r << 4) + l16;
            uint4 v = w4[idx4];
            uint4 mi = ((const uint4*)pc_mask)[idx4];
            if (mi.x) { s1 += sqrtf(__uint_as_float(v.x)); s2 += 1.0f; }
            if (mi.y) { s1 += sqrtf(__uint_as_float(v.y)); s2 += 1.0f; }
            if (mi.z) { s1 += sqrtf(__uint_as_float(v.z)); s2 += 1.0f; }
            if (mi.w) { s1 += sqrtf(__uint_as_float(v.w)); s2 += 1.0f; }
        }
    }
#pragma unroll
    for (int m = 1; m < 16; m <<= 1) {
        s1 += __shfl_xor(s1, m);
        s2 += __shfl_xor(s2, m);
    }
    if (l16 == 0) red[b16] = 0.5f * s1 / s2;

    float sA = 0.0f;
    const uint4* w4d2 = (const uint4*)(ws + D2MIN);
#pragma unroll
    for (int r = 0; r < 16; ++r) {
        uint4 v = w4d2[(r << 8) + t];
        sA += sqrtf(__uint_as_float(v.x)) + sqrtf(__uint_as_float(v.y)) +
              sqrtf(__uint_as_float(v.z)) + sqrtf(__uint_as_float(v.w));
    }
    float sC = 0.0f;
    {
        uint4 v = ((const uint4*)(ws + CDMIN))[t];
        sC += sqrtf(__uint_as_float(v.x)) + sqrtf(__uint_as_float(v.y)) +
              sqrtf(__uint_as_float(v.z)) + sqrtf(__uint_as_float(v.w));
        uint2 v2 = ((const uint2*)(ws + CDMIN + 1024))[t];
        sC += sqrtf(__uint_as_float(v2.x)) + sqrtf(__uint_as_float(v2.y));
    }

    sA = wave_reduce_sum(sA);
    sC = wave_reduce_sum(sC);
    int lane = t & 63, wid = t >> 6;
    if (lane == 0) { sbuf[wid] = sA; sbuf[4 + wid] = sC; }
    __syncthreads();

    if (t == 0) {
        float d2sum = sbuf[0] + sbuf[1] + sbuf[2] + sbuf[3];
        float cdsum = sbuf[4] + sbuf[5] + sbuf[6] + sbuf[7];
        float d1part = 0.0f;
#pragma unroll
        for (int b = 0; b < 16; ++b) d1part += red[b];
        float divs = 0.0f, dels = 0.0f;
#pragma unroll
        for (int q = 0; q < 16; ++q) {
            divs += agent_load_f(ws + S_DIV + q);
            dels += agent_load_f(ws + S_DEL + q);
        }
        float pose  = agent_load_f(ws + S_POSE);
        float nocs  = agent_load_f(ws + S_NOCS) * (1.0f / 1536.0f);
        float dist  = agent_load_f(ws + S_DIST) * (1.0f / 16.0f);
        float recon = d1part * (1.0f / 16.0f) + 0.5f * d2sum * (1.0f / 16384.0f);
        float cd    = cdsum * (1.0f / 1536.0f);
        float divl  = divs * (1.0f / (9120.0f * 16.0f));
        float delta = dels * (1.0f / 16384.0f);
        float all = pose + nocs + cd + divl + recon + delta + dist;
        out[0] = all;  out[1] = pose;  out[2] = nocs;  out[3] = cd;
        out[4] = divl; out[5] = recon; out[6] = delta; out[7] = dist;
    }
}

extern "C" void kernel_launch(void* const* d_in, const int* in_sizes, int n_in,
                              void* d_out, int out_size, void* d_ws, size_t ws_size,
                              hipStream_t stream) {
    float* ws = (float*)d_ws;
    ws_init<<<INIT_U32 / (256 * 4), 256, 0, stream>>>((uint4*)d_ws);
    loss_main<<<NBLOCKS, 256, 0, stream>>>(
        (const float*)d_in[0],  (const float*)d_in[1],  (const float*)d_in[2],
        (const float*)d_in[3],  (const float*)d_in[4],  (const float*)d_in[5],
        (const float*)d_in[6],  (const float*)d_in[7],  (const float*)d_in[8],
        (const float*)d_in[9],  (const float*)d_in[10], (const void*)d_in[11],
        (const float*)d_in[12], (const float*)d_in[13], ws, (float*)d_out);
}

// Round 7
// 17.819 us; speedup vs baseline: 2.2287x; 2.0536x over previous
//
#include <hip/hip_runtime.h>

#define INFV 3.0e38f

// ws slot layout (floats) — every slot written unconditionally each call
#define W_D1S 0     // 128: d1 masked sqrt-sum per (b, ic)   [blk 0..127]
#define W_D1C 128   // 128: mask count per (b, ic)
#define W_D2S 256   // 128: d2 sqrt-sum per (b, jc)          [blk 128..255]
#define W_CD  384   // 16 per b
#define W_DIV 400   // 16
#define W_DEL 416   // 16
#define W_POSE 432
#define W_NOCS 433
#define W_DIST 434

__device__ __forceinline__ float wave_reduce_sum(float v) {
#pragma unroll
    for (int m = 1; m < 64; m <<= 1) v += __shfl_xor(v, m);
    return v;
}

// block-wide sum (256 threads); safe for back-to-back calls
__device__ __forceinline__ float block_sum_t0(float v, float* sbuf) {
    v = wave_reduce_sum(v);
    int lane = threadIdx.x & 63, wid = threadIdx.x >> 6;
    __syncthreads();
    if (lane == 0) sbuf[wid] = v;
    __syncthreads();
    return sbuf[0] + sbuf[1] + sbuf[2] + sbuf[3];
}

// pc_mask may arrive as u8 (1B) or i32 (4B). Probe bytes at 4i+1 (wave-wide).
__device__ __forceinline__ bool mask_mode_u8(const void* mp) {
    const unsigned char* p = (const unsigned char*)mp;
    unsigned char v = p[(threadIdx.x & 63) * 4 + 1];
    return __ballot(v != 0) != 0ull;
}
__device__ __forceinline__ bool mask_at(const void* mp, int idx, bool u8) {
    if (u8) return ((const unsigned char*)mp)[idx] != 0;
    return ((const int*)mp)[idx] != 0;
}

// load a point, derive (-2x,-2y,-2z, ||p||^2)
#define LOADP(Pp, AX, AY, AZ, PP) { \
    float x_ = (Pp)[0], y_ = (Pp)[1], z_ = (Pp)[2]; \
    AX = -2.0f * x_; AY = -2.0f * y_; AZ = -2.0f * z_; \
    PP = fmaf(x_, x_, fmaf(y_, y_, z_ * z_)); }

// min over staged range [j0, j0+len) with 4 parallel accumulators
__device__ __forceinline__ float min_scan(const float4* lds4, int j0, int len,
                                          float ax, float ay, float az) {
    float m0 = INFV, m1 = INFV, m2 = INFV, m3 = INFV;
#pragma unroll 2
    for (int j = j0; j < j0 + len; j += 4) {
        float4 r0 = lds4[j], r1 = lds4[j + 1], r2 = lds4[j + 2], r3 = lds4[j + 3];
        m0 = fminf(m0, fmaf(ax, r0.x, fmaf(ay, r0.y, fmaf(az, r0.z, r0.w))));
        m1 = fminf(m1, fmaf(ax, r1.x, fmaf(ay, r1.y, fmaf(az, r1.z, r1.w))));
        m2 = fminf(m2, fmaf(ax, r2.x, fmaf(ay, r2.y, fmaf(az, r2.z, r2.w))));
        m3 = fminf(m3, fmaf(ax, r3.x, fmaf(ay, r3.y, fmaf(az, r3.z, r3.w))));
    }
    return fminf(fminf(m0, m1), fminf(m2, m3));
}

__global__ __launch_bounds__(256) void loss_main(
    const float* __restrict__ pts,          // (16,1024,3)
    const float* __restrict__ recon_delta,  // (16,1024,3)
    const float* __restrict__ kpt,          // (16,96,3)
    const float* __restrict__ recon,        // (16,1024,3)
    const float* __restrict__ t_label,      // (16,3)
    const float* __restrict__ r_label,      // (16,3,3)
    const float* __restrict__ s_label,      // (16,3)
    const float* __restrict__ pred_r,       // (16,3,3)
    const float* __restrict__ pred_t,       // (16,3)
    const float* __restrict__ pred_s,       // (16,3)
    const float* __restrict__ kpt_nocs,     // (16,96,3)
    const void*  __restrict__ pc_mask,      // (16,1024) bool
    const float* __restrict__ d_pn,         // (16,512)
    const float* __restrict__ d_ul,         // (16,512)
    float* __restrict__ ws)
{
    __shared__ float4 lds4[1024];
    __shared__ float pmin[256];
    __shared__ float sbuf[4];
    const int t = threadIdx.x;
    const int blk = blockIdx.x;

    if (blk < 128) {
        // ---- d1: block=(b, ic of 8). Stage ALL 1024 recon pts of b (16 KB).
        //      2 threads per i (512 j each), LDS pair-combine. No atomics.
        int b = blk >> 3, ic = blk & 7;
        const float* src = recon + (b << 10) * 3;
#pragma unroll
        for (int r = 0; r < 4; ++r) {
            int e = t + (r << 8);
            const float* g = src + e * 3;
            float x = g[0], y = g[1], z = g[2];
            lds4[e] = make_float4(x, y, z, fmaf(x, x, fmaf(y, y, z * z)));
        }
        bool u8 = mask_mode_u8(pc_mask);
        __syncthreads();
        int il = t & 127, q = t >> 7;           // i-local, j-half
        int i = (ic << 7) + il;
        const float* P = pts + ((b << 10) + i) * 3;
        float ax, ay, az, pp;
        LOADP(P, ax, ay, az, pp);
        float smin = min_scan(lds4, q << 9, 512, ax, ay, az);
        pmin[t] = fmaxf(0.0f, pp + smin);
        __syncthreads();
        float contrib_s = 0.0f, contrib_c = 0.0f;
        if (t < 128) {
            float d = sqrtf(fminf(pmin[t], pmin[t + 128]));
            float mv = mask_at(pc_mask, (b << 10) + i, u8) ? 1.0f : 0.0f;
            contrib_s = d * mv;
            contrib_c = mv;
        }
        float s = block_sum_t0(contrib_s, sbuf);
        float c = block_sum_t0(contrib_c, sbuf);
        if (t == 0) { ws[W_D1S + blk] = s; ws[W_D1C + blk] = c; }

    } else if (blk < 256) {
        // ---- d2: block=(b, jc of 8). Stage ALL 1024 pts (masked->(0,0,0,3e36)).
        int bb = blk - 128;
        int b = bb >> 3, jc = bb & 7;
        bool u8 = mask_mode_u8(pc_mask);
        const float* src = pts + (b << 10) * 3;
#pragma unroll
        for (int r = 0; r < 4; ++r) {
            int e = t + (r << 8);
            const float* g = src + e * 3;
            bool m = mask_at(pc_mask, (b << 10) + e, u8);
            float x = g[0], y = g[1], z = g[2];
            lds4[e] = m ? make_float4(x, y, z, fmaf(x, x, fmaf(y, y, z * z)))
                        : make_float4(0.0f, 0.0f, 0.0f, 3.0e36f);
        }
        __syncthreads();
        int jl = t & 127, q = t >> 7;
        int j = (jc << 7) + jl;
        const float* R = recon + ((b << 10) + j) * 3;
        float ax, ay, az, pp;
        LOADP(R, ax, ay, az, pp);
        float smin = min_scan(lds4, q << 9, 512, ax, ay, az);
        pmin[t] = fmaxf(0.0f, pp + smin);
        __syncthreads();
        float contrib = 0.0f;
        if (t < 128) contrib = sqrtf(fminf(pmin[t], pmin[t + 128]));
        float s = block_sum_t0(contrib, sbuf);
        if (t == 0) ws[W_D2S + bb] = s;

    } else if (blk < 272) {
        // ---- cd: block = b. Stage all 1024 pts; 2 threads per k (512 j each).
        int b = blk - 256;
        const float* src = pts + (b << 10) * 3;
#pragma unroll
        for (int r = 0; r < 4; ++r) {
            int e = t + (r << 8);
            const float* g = src + e * 3;
            float x = g[0], y = g[1], z = g[2];
            lds4[e] = make_float4(x, y, z, fmaf(x, x, fmaf(y, y, z * z)));
        }
        __syncthreads();
        if (t < 192) {
            int q = t / 96, k = t - q * 96;
            const float* K = kpt + (b * 96 + k) * 3;
            float ax, ay, az, pp;
            LOADP(K, ax, ay, az, pp);
            float smin = min_scan(lds4, q << 9, 512, ax, ay, az);
            pmin[t] = fmaxf(0.0f, pp + smin);
        }
        __syncthreads();
        float contrib = 0.0f;
        if (t < 96) contrib = sqrtf(fminf(pmin[t], pmin[t + 96]));
        float s = block_sum_t0(contrib, sbuf);
        if (t == 0) ws[W_CD + b] = s;

    } else if (blk < 288) {
        // ---- diversity per batch
        int b = blk - 272;
        const float* K = kpt + b * 288;
        if (t < 96) lds4[t] = make_float4(K[t * 3], K[t * 3 + 1], K[t * 3 + 2], 0.0f);
        __syncthreads();
        float acc = 0.0f;
        for (int r = 0; r < 36; ++r) {
            int p = r * 256 + t;
            int ki = p / 96, kj = p - ki * 96;
            float4 a = lds4[ki], c = lds4[kj];
            float dx = a.x - c.x, dy = a.y - c.y, dz = a.z - c.z;
            float d = sqrtf(dx * dx + dy * dy + dz * dz + 1e-12f);
            if (ki != kj && d < 0.1f) acc += 1.0f - d * 10.0f;
        }
        float s = block_sum_t0(acc, sbuf);
        if (t == 0) ws[W_DIV + b] = s;

    } else if (blk < 304) {
        // ---- recon_delta norms
        int e = blk - 288;
        float acc = 0.0f;
#pragma unroll
        for (int r = 0; r < 4; ++r) {
            const float* D = recon_delta + (e * 1024 + r * 256 + t) * 3;
            acc += sqrtf(D[0] * D[0] + D[1] * D[1] + D[2] * D[2]);
        }
        float s = block_sum_t0(acc, sbuf);
        if (t == 0) ws[W_DEL + e] = s;

    } else if (blk == 304) {
        // ---- pose (fully normalized)
        float c = 0.0f;
        if (t < 48) {
            int b = t / 3, j = t - b * 3;
            float s = 0.0f;
#pragma unroll
            for (int i2 = 0; i2 < 3; ++i2) {
                float d = pred_r[b * 9 + i2 * 3 + j] - r_label[b * 9 + i2 * 3 + j];
                s += d * d;
            }
            c = sqrtf(s) * (1.0f / 48.0f);
        } else if (t >= 64 && t < 80) {
            int b = t - 64;
            float s = 0.0f;
#pragma unroll
            for (int d2i = 0; d2i < 3; ++d2i) {
                float d = pred_t[b * 3 + d2i] - t_label[b * 3 + d2i];
                s += d * d;
            }
            c = sqrtf(s) * (1.0f / 16.0f);
        } else if (t >= 96 && t < 112) {
            int b = t - 96;
            float s = 0.0f;
#pragma unroll
            for (int d2i = 0; d2i < 3; ++d2i) {
                float d = pred_s[b * 3 + d2i] - s_label[b * 3 + d2i];
                s += d * d;
            }
            c = sqrtf(s) * (1.0f / 16.0f);
        }
        float s = block_sum_t0(c, sbuf);
        if (t == 0) ws[W_POSE] = s;

    } else if (blk == 305) {
        // ---- NOCS smooth-L1
        float acc = 0.0f;
#pragma unroll
        for (int r = 0; r < 6; ++r) {
            int item = r * 256 + t;
            int b = item / 96, k = item - b * 96;
            float sx = s_label[b * 3], sy = s_label[b * 3 + 1], sz = s_label[b * 3 + 2];
            float sn = sqrtf(sx * sx + sy * sy + sz * sz) + 1e-8f;
            float v0 = (kpt[(b * 96 + k) * 3 + 0] - t_label[b * 3 + 0]) / sn;
            float v1 = (kpt[(b * 96 + k) * 3 + 1] - t_label[b * 3 + 1]) / sn;
            float v2 = (kpt[(b * 96 + k) * 3 + 2] - t_label[b * 3 + 2]) / sn;
#pragma unroll
            for (int e = 0; e < 3; ++e) {
                float gt = v0 * r_label[b * 9 + e] + v1 * r_label[b * 9 + 3 + e] +
                           v2 * r_label[b * 9 + 6 + e];
                float diff = fabsf(kpt_nocs[(b * 96 + k) * 3 + e] - gt);
                acc += (diff > 0.1f) ? (diff - 0.05f) : (diff * diff * 5.0f);
            }
        }
        float s = block_sum_t0(acc, sbuf);
        if (t == 0) ws[W_NOCS] = s;

    } else {
        // ---- distillation
        int b = t >> 4, off = t & 15;
        float s = 0.0f;
        for (int c2 = off; c2 < 512; c2 += 16) {
            float d = d_pn[b * 512 + c2] - d_ul[b * 512 + c2];
            s += d * d;
        }
        s += __shfl_xor(s, 1);
        s += __shfl_xor(s, 2);
        s += __shfl_xor(s, 4);
        s += __shfl_xor(s, 8);
        float c = (off == 0) ? sqrtf(s) : 0.0f;
        float sm = block_sum_t0(c, sbuf);
        if (t == 0) ws[W_DIST] = sm;
    }
}

__global__ __launch_bounds__(64) void loss_finalize(const float* __restrict__ ws,
                                                    float* __restrict__ out) {
    int t = threadIdx.x;

    float vd1 = 0.0f;
    if (t < 16) {
        float s = 0.0f, c = 0.0f;
#pragma unroll
        for (int ic = 0; ic < 8; ++ic) {
            s += ws[W_D1S + t * 8 + ic];
            c += ws[W_D1C + t * 8 + ic];
        }
        vd1 = 0.5f * s / c;
    }
    vd1 = wave_reduce_sum(vd1);

    float vd2 = ws[W_D2S + t] + ws[W_D2S + 64 + t];
    vd2 = wave_reduce_sum(vd2);

    float vcd = (t < 16) ? ws[W_CD + t] : 0.0f;
    vcd = wave_reduce_sum(vcd);

    float vdv = (t < 16) ? ws[W_DIV + t] : 0.0f;
    vdv = wave_reduce_sum(vdv);

    float vdl = (t < 16) ? ws[W_DEL + t] : 0.0f;
    vdl = wave_reduce_sum(vdl);

    if (t == 0) {
        float pose  = ws[W_POSE];
        float nocs  = ws[W_NOCS] * (1.0f / 1536.0f);
        float dist  = ws[W_DIST] * (1.0f / 16.0f);
        float recon = vd1 * (1.0f / 16.0f) + 0.5f * vd2 * (1.0f / 16384.0f);
        float cd    = vcd * (1.0f / 1536.0f);
        float divl  = vdv * (1.0f / (9120.0f * 16.0f));
        float delta = vdl * (1.0f / 16384.0f);
        float all = pose + nocs + cd + divl + recon + delta + dist;
        out[0] = all;  out[1] = pose;  out[2] = nocs;  out[3] = cd;
        out[4] = divl; out[5] = recon; out[6] = delta; out[7] = dist;
    }
}

extern "C" void kernel_launch(void* const* d_in, const int* in_sizes, int n_in,
                              void* d_out, int out_size, void* d_ws, size_t ws_size,
                              hipStream_t stream) {
    float* ws = (float*)d_ws;
    loss_main<<<307, 256, 0, stream>>>(
        (const float*)d_in[0],  (const float*)d_in[1],  (const float*)d_in[2],
        (const float*)d_in[3],  (const float*)d_in[4],  (const float*)d_in[5],
        (const float*)d_in[6],  (const float*)d_in[7],  (const float*)d_in[8],
        (const float*)d_in[9],  (const float*)d_in[10], (const void*)d_in[11],
        (const float*)d_in[12], (const float*)d_in[13], ws);
    loss_finalize<<<1, 64, 0, stream>>>(ws, (float*)d_out);
}

// Round 8
// 15.933 us; speedup vs baseline: 2.4926x; 1.1184x over previous
//
#include <hip/hip_runtime.h>

#define INFV 3.0e38f

// ws slot layout (floats) — every slot written unconditionally each call
#define W_D1S 0     // 128: d1 masked sqrt-sum per (b, ic)   [blk 0..127]
#define W_D1C 128   // 128: mask count per (b, ic)
#define W_D2S 256   // 128: d2 sqrt-sum per (b, jc)          [blk 128..255]
#define W_CD  384   // 16 per b
#define W_DIV 400   // 16
#define W_DEL 416   // 16
#define W_POSE 432
#define W_NOCS 433
#define W_DIST 434

__device__ __forceinline__ float wave_reduce_sum(float v) {
#pragma unroll
    for (int m = 1; m < 64; m <<= 1) v += __shfl_xor(v, m);
    return v;
}

// block-wide sum (256 threads); safe for back-to-back calls
__device__ __forceinline__ float block_sum_t0(float v, float* sbuf) {
    v = wave_reduce_sum(v);
    int lane = threadIdx.x & 63, wid = threadIdx.x >> 6;
    __syncthreads();
    if (lane == 0) sbuf[wid] = v;
    __syncthreads();
    return sbuf[0] + sbuf[1] + sbuf[2] + sbuf[3];
}

// pc_mask may arrive as u8 (1B) or i32 (4B). Probe bytes at 4i+1 (wave-wide).
__device__ __forceinline__ bool mask_mode_u8(const void* mp) {
    const unsigned char* p = (const unsigned char*)mp;
    unsigned char v = p[(threadIdx.x & 63) * 4 + 1];
    return __ballot(v != 0) != 0ull;
}
__device__ __forceinline__ bool mask_at(const void* mp, int idx, bool u8) {
    if (u8) return ((const unsigned char*)mp)[idx] != 0;
    return ((const int*)mp)[idx] != 0;
}

// load a point, derive (-2x,-2y,-2z, ||p||^2)
#define LOADP(Pp, AX, AY, AZ, PP) { \
    float x_ = (Pp)[0], y_ = (Pp)[1], z_ = (Pp)[2]; \
    AX = -2.0f * x_; AY = -2.0f * y_; AZ = -2.0f * z_; \
    PP = fmaf(x_, x_, fmaf(y_, y_, z_ * z_)); }

__global__ __launch_bounds__(256) void loss_main(
    const float* __restrict__ pts,          // (16,1024,3)
    const float* __restrict__ recon_delta,  // (16,1024,3)
    const float* __restrict__ kpt,          // (16,96,3)
    const float* __restrict__ recon,        // (16,1024,3)
    const float* __restrict__ t_label,      // (16,3)
    const float* __restrict__ r_label,      // (16,3,3)
    const float* __restrict__ s_label,      // (16,3)
    const float* __restrict__ pred_r,       // (16,3,3)
    const float* __restrict__ pred_t,       // (16,3)
    const float* __restrict__ pred_s,       // (16,3)
    const float* __restrict__ kpt_nocs,     // (16,96,3)
    const void*  __restrict__ pc_mask,      // (16,1024) bool
    const float* __restrict__ d_pn,         // (16,512)
    const float* __restrict__ d_ul,         // (16,512)
    float* __restrict__ ws)
{
    __shared__ float4 lds4[1024];
    __shared__ float pminS[2176];   // 128 rows x stride 17 (pad -> conflict-free)
    __shared__ float sbuf[4];
    const int t = threadIdx.x;
    const int blk = blockIdx.x;

    if (blk < 128) {
        // ---- d1: block=(b, ic of 8). Stage ALL 1024 recon pts of b (16 KB).
        //      thread = (i-group of 8) x (j-class of 16, stride-16 interleave).
        int b = blk >> 3, ic = blk & 7;
        const float* src = recon + (b << 10) * 3;
#pragma unroll
        for (int r = 0; r < 4; ++r) {
            int e = t + (r << 8);
            const float* g = src + e * 3;
            float x = g[0], y = g[1], z = g[2];
            lds4[e] = make_float4(x, y, z, fmaf(x, x, fmaf(y, y, z * z)));
        }
        bool u8 = mask_mode_u8(pc_mask);
        __syncthreads();
        int tg = t >> 4, jc = t & 15;
        int i0 = (ic << 7) + (tg << 3);
        float ax[8], ay[8], az[8], pw[8], mm[8];
#pragma unroll
        for (int u = 0; u < 8; ++u) {
            const float* P = pts + ((b << 10) + i0 + u) * 3;
            LOADP(P, ax[u], ay[u], az[u], pw[u]);
            mm[u] = INFV;
        }
#pragma unroll 2
        for (int r = 0; r < 64; ++r) {
            float4 q = lds4[(r << 4) + jc];
#pragma unroll
            for (int u = 0; u < 8; ++u)
                mm[u] = fminf(mm[u],
                              fmaf(ax[u], q.x, fmaf(ay[u], q.y, fmaf(az[u], q.z, q.w))));
        }
#pragma unroll
        for (int u = 0; u < 8; ++u)
            pminS[(tg * 8 + u) * 17 + jc] = pw[u] + mm[u];
        __syncthreads();
        float contrib_s = 0.0f, contrib_c = 0.0f;
        if (t < 128) {
            float v = INFV;
#pragma unroll
            for (int c = 0; c < 16; ++c) v = fminf(v, pminS[t * 17 + c]);
            float d = sqrtf(fmaxf(0.0f, v));
            float mv = mask_at(pc_mask, (b << 10) + (ic << 7) + t, u8) ? 1.0f : 0.0f;
            contrib_s = d * mv;
            contrib_c = mv;
        }
        float s = block_sum_t0(contrib_s, sbuf);
        float c = block_sum_t0(contrib_c, sbuf);
        if (t == 0) { ws[W_D1S + blk] = s; ws[W_D1C + blk] = c; }

    } else if (blk < 256) {
        // ---- d2: block=(b, jc of 8). Stage ALL 1024 pts (masked->(0,0,0,3e36)).
        int bb = blk - 128;
        int b = bb >> 3, ocl = bb & 7;
        bool u8 = mask_mode_u8(pc_mask);
        const float* src = pts + (b << 10) * 3;
#pragma unroll
        for (int r = 0; r < 4; ++r) {
            int e = t + (r << 8);
            const float* g = src + e * 3;
            bool m = mask_at(pc_mask, (b << 10) + e, u8);
            float x = g[0], y = g[1], z = g[2];
            lds4[e] = m ? make_float4(x, y, z, fmaf(x, x, fmaf(y, y, z * z)))
                        : make_float4(0.0f, 0.0f, 0.0f, 3.0e36f);
        }
        __syncthreads();
        int tg = t >> 4, jc = t & 15;
        int j0 = (ocl << 7) + (tg << 3);
        float ax[8], ay[8], az[8], pw[8], mm[8];
#pragma unroll
        for (int u = 0; u < 8; ++u) {
            const float* R = recon + ((b << 10) + j0 + u) * 3;
            LOADP(R, ax[u], ay[u], az[u], pw[u]);
            mm[u] = INFV;
        }
#pragma unroll 2
        for (int r = 0; r < 64; ++r) {
            float4 q = lds4[(r << 4) + jc];
#pragma unroll
            for (int u = 0; u < 8; ++u)
                mm[u] = fminf(mm[u],
                              fmaf(ax[u], q.x, fmaf(ay[u], q.y, fmaf(az[u], q.z, q.w))));
        }
#pragma unroll
        for (int u = 0; u < 8; ++u)
            pminS[(tg * 8 + u) * 17 + jc] = pw[u] + mm[u];
        __syncthreads();
        float contrib = 0.0f;
        if (t < 128) {
            float v = INFV;
#pragma unroll
            for (int c = 0; c < 16; ++c) v = fminf(v, pminS[t * 17 + c]);
            contrib = sqrtf(fmaxf(0.0f, v));
        }
        float s = block_sum_t0(contrib, sbuf);
        if (t == 0) ws[W_D2S + bb] = s;

    } else if (blk < 272) {
        // ---- cd: block = b. Stage all 1024 pts; thread = (k-group of 8) x class.
        int b = blk - 256;
        const float* src = pts + (b << 10) * 3;
#pragma unroll
        for (int r = 0; r < 4; ++r) {
            int e = t + (r << 8);
            const float* g = src + e * 3;
            float x = g[0], y = g[1], z = g[2];
            lds4[e] = make_float4(x, y, z, fmaf(x, x, fmaf(y, y, z * z)));
        }
        __syncthreads();
        int kg = t >> 4, jc = t & 15;
        if (kg < 12) {
            int k0 = kg << 3;
            float ax[8], ay[8], az[8], pw[8], mm[8];
#pragma unroll
            for (int u = 0; u < 8; ++u) {
                const float* K = kpt + (b * 96 + k0 + u) * 3;
                LOADP(K, ax[u], ay[u], az[u], pw[u]);
                mm[u] = INFV;
            }
#pragma unroll 2
            for (int r = 0; r < 64; ++r) {
                float4 q = lds4[(r << 4) + jc];
#pragma unroll
                for (int u = 0; u < 8; ++u)
                    mm[u] = fminf(mm[u],
                                  fmaf(ax[u], q.x, fmaf(ay[u], q.y, fmaf(az[u], q.z, q.w))));
            }
#pragma unroll
            for (int u = 0; u < 8; ++u)
                pminS[(kg * 8 + u) * 17 + jc] = pw[u] + mm[u];
        }
        __syncthreads();
        float contrib = 0.0f;
        if (t < 96) {
            float v = INFV;
#pragma unroll
            for (int c = 0; c < 16; ++c) v = fminf(v, pminS[t * 17 + c]);
            contrib = sqrtf(fmaxf(0.0f, v));
        }
        float s = block_sum_t0(contrib, sbuf);
        if (t == 0) ws[W_CD + b] = s;

    } else if (blk < 288) {
        // ---- diversity per batch
        int b = blk - 272;
        const float* K = kpt + b * 288;
        if (t < 96) lds4[t] = make_float4(K[t * 3], K[t * 3 + 1], K[t * 3 + 2], 0.0f);
        __syncthreads();
        float acc = 0.0f;
        for (int r = 0; r < 36; ++r) {
            int p = r * 256 + t;
            int ki = p / 96, kj = p - ki * 96;
            float4 a = lds4[ki], c = lds4[kj];
            float dx = a.x - c.x, dy = a.y - c.y, dz = a.z - c.z;
            float d = sqrtf(dx * dx + dy * dy + dz * dz + 1e-12f);
            if (ki != kj && d < 0.1f) acc += 1.0f - d * 10.0f;
        }
        float s = block_sum_t0(acc, sbuf);
        if (t == 0) ws[W_DIV + b] = s;

    } else if (blk < 304) {
        // ---- recon_delta norms
        int e = blk - 288;
        float acc = 0.0f;
#pragma unroll
        for (int r = 0; r < 4; ++r) {
            const float* D = recon_delta + (e * 1024 + r * 256 + t) * 3;
            acc += sqrtf(D[0] * D[0] + D[1] * D[1] + D[2] * D[2]);
        }
        float s = block_sum_t0(acc, sbuf);
        if (t == 0) ws[W_DEL + e] = s;

    } else if (blk == 304) {
        // ---- pose (fully normalized)
        float c = 0.0f;
        if (t < 48) {
            int b = t / 3, j = t - b * 3;
            float s = 0.0f;
#pragma unroll
            for (int i2 = 0; i2 < 3; ++i2) {
                float d = pred_r[b * 9 + i2 * 3 + j] - r_label[b * 9 + i2 * 3 + j];
                s += d * d;
            }
            c = sqrtf(s) * (1.0f / 48.0f);
        } else if (t >= 64 && t < 80) {
            int b = t - 64;
            float s = 0.0f;
#pragma unroll
            for (int d2i = 0; d2i < 3; ++d2i) {
                float d = pred_t[b * 3 + d2i] - t_label[b * 3 + d2i];
                s += d * d;
            }
            c = sqrtf(s) * (1.0f / 16.0f);
        } else if (t >= 96 && t < 112) {
            int b = t - 96;
            float s = 0.0f;
#pragma unroll
            for (int d2i = 0; d2i < 3; ++d2i) {
                float d = pred_s[b * 3 + d2i] - s_label[b * 3 + d2i];
                s += d * d;
            }
            c = sqrtf(s) * (1.0f / 16.0f);
        }
        float s = block_sum_t0(c, sbuf);
        if (t == 0) ws[W_POSE] = s;

    } else if (blk == 305) {
        // ---- NOCS smooth-L1
        float acc = 0.0f;
#pragma unroll
        for (int r = 0; r < 6; ++r) {
            int item = r * 256 + t;
            int b = item / 96, k = item - b * 96;
            float sx = s_label[b * 3], sy = s_label[b * 3 + 1], sz = s_label[b * 3 + 2];
            float sn = sqrtf(sx * sx + sy * sy + sz * sz) + 1e-8f;
            float v0 = (kpt[(b * 96 + k) * 3 + 0] - t_label[b * 3 + 0]) / sn;
            float v1 = (kpt[(b * 96 + k) * 3 + 1] - t_label[b * 3 + 1]) / sn;
            float v2 = (kpt[(b * 96 + k) * 3 + 2] - t_label[b * 3 + 2]) / sn;
#pragma unroll
            for (int e = 0; e < 3; ++e) {
                float gt = v0 * r_label[b * 9 + e] + v1 * r_label[b * 9 + 3 + e] +
                           v2 * r_label[b * 9 + 6 + e];
                float diff = fabsf(kpt_nocs[(b * 96 + k) * 3 + e] - gt);
                acc += (diff > 0.1f) ? (diff - 0.05f) : (diff * diff * 5.0f);
            }
        }
        float s = block_sum_t0(acc, sbuf);
        if (t == 0) ws[W_NOCS] = s;

    } else {
        // ---- distillation
        int b = t >> 4, off = t & 15;
        float s = 0.0f;
        for (int c2 = off; c2 < 512; c2 += 16) {
            float d = d_pn[b * 512 + c2] - d_ul[b * 512 + c2];
            s += d * d;
        }
        s += __shfl_xor(s, 1);
        s += __shfl_xor(s, 2);
        s += __shfl_xor(s, 4);
        s += __shfl_xor(s, 8);
        float c = (off == 0) ? sqrtf(s) : 0.0f;
        float sm = block_sum_t0(c, sbuf);
        if (t == 0) ws[W_DIST] = sm;
    }
}

__global__ __launch_bounds__(64) void loss_finalize(const float* __restrict__ ws,
                                                    float* __restrict__ out) {
    int t = threadIdx.x;

    float vd1 = 0.0f;
    if (t < 16) {
        float s = 0.0f, c = 0.0f;
#pragma unroll
        for (int ic = 0; ic < 8; ++ic) {
            s += ws[W_D1S + t * 8 + ic];
            c += ws[W_D1C + t * 8 + ic];
        }
        vd1 = 0.5f * s / c;
    }
    vd1 = wave_reduce_sum(vd1);

    float vd2 = ws[W_D2S + t] + ws[W_D2S + 64 + t];
    vd2 = wave_reduce_sum(vd2);

    float vcd = (t < 16) ? ws[W_CD + t] : 0.0f;
    vcd = wave_reduce_sum(vcd);

    float vdv = (t < 16) ? ws[W_DIV + t] : 0.0f;
    vdv = wave_reduce_sum(vdv);

    float vdl = (t < 16) ? ws[W_DEL + t] : 0.0f;
    vdl = wave_reduce_sum(vdl);

    if (t == 0) {
        float pose  = ws[W_POSE];
        float nocs  = ws[W_NOCS] * (1.0f / 1536.0f);
        float dist  = ws[W_DIST] * (1.0f / 16.0f);
        float recon = vd1 * (1.0f / 16.0f) + 0.5f * vd2 * (1.0f / 16384.0f);
        float cd    = vcd * (1.0f / 1536.0f);
        float divl  = vdv * (1.0f / (9120.0f * 16.0f));
        float delta = vdl * (1.0f / 16384.0f);
        float all = pose + nocs + cd + divl + recon + delta + dist;
        out[0] = all;  out[1] = pose;  out[2] = nocs;  out[3] = cd;
        out[4] = divl; out[5] = recon; out[6] = delta; out[7] = dist;
    }
}

extern "C" void kernel_launch(void* const* d_in, const int* in_sizes, int n_in,
                              void* d_out, int out_size, void* d_ws, size_t ws_size,
                              hipStream_t stream) {
    float* ws = (float*)d_ws;
    loss_main<<<307, 256, 0, stream>>>(
        (const float*)d_in[0],  (const float*)d_in[1],  (const float*)d_in[2],
        (const float*)d_in[3],  (const float*)d_in[4],  (const float*)d_in[5],
        (const float*)d_in[6],  (const float*)d_in[7],  (const float*)d_in[8],
        (const float*)d_in[9],  (const float*)d_in[10], (const void*)d_in[11],
        (const float*)d_in[12], (const float*)d_in[13], ws);
    loss_finalize<<<1, 64, 0, stream>>>(ws, (float*)d_out);
}